// Round 9
// baseline (810.925 us; speedup 1.0000x reference)
//
#include <hip/hip_runtime.h>
#include <hip/hip_bf16.h>
#include <math.h>

#define HWSZ 65536
#define NPIX 131072
#define LDA 208

typedef __attribute__((ext_vector_type(8))) short short8;
typedef __attribute__((ext_vector_type(4))) float f32x4;
typedef __attribute__((ext_vector_type(16))) float f32x16;

__device__ __forceinline__ float sigmf(float x){ return 1.f/(1.f+__expf(-x)); }
__device__ __forceinline__ float tanhf2(float x){
  x = fminf(fmaxf(x,-15.f),15.f);
  float e = __expf(2.f*x);
  return (e-1.f)/(e+1.f);
}
__device__ __forceinline__ unsigned short f2b(float f){
  __hip_bfloat16 b = __float2bfloat16(f);
  return *(unsigned short*)&b;
}
__device__ __forceinline__ float b2f(unsigned short u){
  unsigned int v = ((unsigned int)u)<<16;
  return __uint_as_float(v);
}

// ---------------- weight prep ----------------
__global__ void prep_gru_wb(const float* __restrict__ wih, const float* __restrict__ whh,
                            unsigned short* __restrict__ WG){
  int idx = blockIdx.x*256+threadIdx.x;
  if(idx >= 6*384*32) return;
  int kq = idx&31; int r = idx>>5;
  int c = r%384; int ch = r/384;
  int k = ch*32+kq;
  float v = (k<64) ? wih[c*64+k] : whh[c*128+(k-64)];
  WG[idx] = f2b(v);
}

// 16x16-path conv weights: [tap][chunk(ICP/32)][oc][32] bf16, zero-padded ic>=IC
__global__ void prep_conv_w(const float* __restrict__ src, unsigned short* __restrict__ dst,
                            int IC, int ICC, int OC, int KS, int total){
  int idx = blockIdx.x*256+threadIdx.x;
  if(idx>=total) return;
  int icq = idx&31; int r = idx>>5;
  int oc = r%OC; r/=OC;
  int ch = r%ICC; int tap = r/ICC;
  int ky = tap/KS, kx = tap%KS;
  int ic = ch*32+icq;
  float v = (ic<IC)? src[((oc*IC+ic)*KS+ky)*KS+kx] : 0.f;
  dst[idx] = f2b(v);
}

// 32x32-path conv weights: [tap][chunk(IC/16)][oc][16] bf16 (IC multiple of 16)
__global__ void prep_conv_w32(const float* __restrict__ src, unsigned short* __restrict__ dst,
                              int IC, int OC, int KS, int total){
  int idx = blockIdx.x*256+threadIdx.x;
  if(idx>=total) return;
  int q = idx&15; int r = idx>>4;
  int oc = r%OC; r/=OC;
  int ICC = IC/16;
  int ch = r%ICC; int tap = r/ICC;
  int ky = tap/KS, kx = tap%KS;
  int ic = ch*16+q;
  dst[idx] = f2b(src[((oc*IC+ic)*KS+ky)*KS+kx]);
}

// ---------------- mask reductions ----------------
__global__ void flags_kernel(const int* __restrict__ masks, int* __restrict__ flags){
  __shared__ int red[256];
  int b = blockIdx.x; int acc=0;
  const int* m = masks + b*HWSZ;
  for(int i=threadIdx.x;i<HWSZ;i+=256) acc |= (m[i]>0)?1:0;
  red[threadIdx.x]=acc; __syncthreads();
  for(int s=128;s>0;s>>=1){ if(threadIdx.x<s) red[threadIdx.x]|=red[threadIdx.x+s]; __syncthreads(); }
  if(threadIdx.x==0) flags[b]=red[0];
}

__global__ void obs_kernel(const int* __restrict__ masks, const int* __restrict__ flags,
                           float* __restrict__ out){
  int p = blockIdx.x*256+threadIdx.x;
  if(p>=NPIX) return;
  int n = p>>16, hw = p&65535;
  int s=0;
  #pragma unroll
  for(int t=0;t<4;t++) s += masks[((n*4+t)<<16)+hw]*flags[n*4+t];
  out[p]=(float)s;
}

// ---------------- GRU via MFMA: 512 threads, 8 waves, 32 px per block ----------------
__launch_bounds__(512,4)
__global__ void gru_mfma(const float* __restrict__ feat, const int* __restrict__ masks,
                         const unsigned short* __restrict__ WG,
                         const float* __restrict__ bih, const float* __restrict__ bhh,
                         unsigned short* __restrict__ S){
  __shared__ __align__(16) unsigned short ax[32*LDA];
  __shared__ int msk[32];
  const int tid=threadIdx.x, wv=tid>>6, lane=tid&63, l15=lane&15, quad=lane>>4;
  const int p0=blockIdx.x*32;
  const int n=p0>>16, hw0=p0&65535;
  const int j16=wv*16;

  const int j=j16+l15;
  const float brv = bih[j]     + bhh[j];
  const float bzv = bih[128+j] + bhh[128+j];
  const float binv= bih[256+j];
  const float bhnv= bhh[256+j];

  float4 z4={0.f,0.f,0.f,0.f};
  { int px=tid>>4, c8=tid&15; *(float4*)&ax[px*LDA+64+c8*8]=z4; }

  for(int t=0;t<4;t++){
    __syncthreads();
    { int px=tid>>4, c4=tid&15;
      float4 v=*(const float4*)&feat[(size_t)(((n*4+t)<<16)|(hw0+px))*64 + c4*4];
      ushort4 u; u.x=f2b(v.x);u.y=f2b(v.y);u.z=f2b(v.z);u.w=f2b(v.w);
      *(ushort4*)&ax[px*LDA+c4*4]=u;
    }
    if(tid<32) msk[tid]=masks[((n*4+t)<<16)+hw0+tid];
    __syncthreads();

    f32x4 aR[2],aZ[2],aNX[2],aNH[2];
    #pragma unroll
    for(int mt=0;mt<2;mt++){
      f32x4 zz={0.f,0.f,0.f,0.f};
      aR[mt]=zz; aZ[mt]=zz; aNX[mt]=zz; aNH[mt]=zz;
    }

    #pragma unroll
    for(int ch=0;ch<6;ch++){
      short8 a[2];
      #pragma unroll
      for(int mt=0;mt<2;mt++)
        a[mt]=*(const short8*)&ax[(mt*16+l15)*LDA + ch*32 + quad*8];
      const unsigned short* bb = WG + (((size_t)(ch*384 + l15))<<5) + quad*8;
      short8 bR=*(const short8*)(bb + (((size_t)(     j16))<<5));
      short8 bZ=*(const short8*)(bb + (((size_t)(128+j16))<<5));
      short8 bN=*(const short8*)(bb + (((size_t)(256+j16))<<5));
      #pragma unroll
      for(int mt=0;mt<2;mt++){
        aR[mt]=__builtin_amdgcn_mfma_f32_16x16x32_bf16(a[mt],bR,aR[mt],0,0,0);
        aZ[mt]=__builtin_amdgcn_mfma_f32_16x16x32_bf16(a[mt],bZ,aZ[mt],0,0,0);
        if(ch<2)
          aNX[mt]=__builtin_amdgcn_mfma_f32_16x16x32_bf16(a[mt],bN,aNX[mt],0,0,0);
        else
          aNH[mt]=__builtin_amdgcn_mfma_f32_16x16x32_bf16(a[mt],bN,aNH[mt],0,0,0);
      }
    }
    __syncthreads();

    #pragma unroll
    for(int mt=0;mt<2;mt++){
      #pragma unroll
      for(int r=0;r<4;r++){
        int px=mt*16+quad*4+r;
        float rg=sigmf(aR[mt][r]+brv);
        float zg=sigmf(aZ[mt][r]+bzv);
        float nn=tanhf2(aNX[mt][r]+binv+rg*(aNH[mt][r]+bhnv));
        unsigned short hu=ax[px*LDA+64+j];
        float hold=b2f(hu);
        float h2=(1.f-zg)*nn+zg*hold;
        ax[px*LDA+64+j] = (msk[px]>0)? f2b(h2) : hu;
      }
    }
  }
  __syncthreads();
  { int px=tid>>4, c8=tid&15;
    *(float4*)&S[(size_t)(p0+px)*128 + c8*8] = *(float4*)&ax[px*LDA+64+c8*8];
  }
}

// ---------------- 32x32 MFMA implicit-GEMM conv (conv1/conv2) ----------------
// 256 threads, 4 waves; wave wv owns m-tile [wv*32, wv*32+32) x ALL OC.
// Per K-step (K=16): ONE A ds_read_b128 reused by NTW MFMAs -> minimal LDS traffic.
template<int IC,int OC,int KS>
__launch_bounds__(256,3)
__global__ void m32conv(const unsigned short* __restrict__ in, const unsigned short* __restrict__ Wb,
                        unsigned short* __restrict__ out, float* __restrict__ partials){
  constexpr int P=KS/2, ROWS=128+KS-1, LDR=IC+8, ICC=IC/16, C8=IC/8;
  constexpr int NTW=OC/32, NS=KS*ICC;
  __shared__ __align__(16) unsigned short lds[ROWS*LDR];
  const int tid=threadIdx.x;
  const int wv=tid>>6, lane=tid&63, l31=lane&31, hf=lane>>5;
  const int p0=blockIdx.x*128;
  const int n=p0>>16; const int hw0=p0&65535; const int y0=hw0>>8, x0=hw0&255;
  const int m0=wv*32;

  f32x16 acc[NTW];
  #pragma unroll
  for(int nn=0;nn<NTW;nn++){
    #pragma unroll
    for(int r=0;r<16;r++) acc[nn][r]=0.f;
  }

  for(int ky=0;ky<KS;ky++){
    int ys=y0+ky-P;
    if(ys<0||ys>255) continue;          // uniform across block
    __syncthreads();
    for(int i=tid;i<ROWS*C8;i+=256){
      int c8=i%C8, px=i/C8;
      int xg=x0-P+px;
      float4 v={0.f,0.f,0.f,0.f};
      if(xg>=0 && xg<256)
        v = *(const float4*)(in + (size_t)(((n<<16)|(ys<<8))+xg)*IC + c8*8);
      *(float4*)&lds[px*LDR + c8*8] = v;
    }
    __syncthreads();

    // software-pipelined K loop over (kx, ic16-chunk)
    short8 Bn[NTW];
    {
      const unsigned short* bp = Wb + (((size_t)((ky*KS+0)*ICC+0)*OC + l31)<<4) + hf*8;
      #pragma unroll
      for(int nn=0;nn<NTW;nn++) Bn[nn]=*(const short8*)(bp + (nn<<9));
    }
    #pragma unroll
    for(int s=0;s<NS;s++){
      const int kx=s/ICC, ch=s%ICC;
      short8 Bc[NTW];
      #pragma unroll
      for(int nn=0;nn<NTW;nn++) Bc[nn]=Bn[nn];
      if(s+1<NS){
        const int kx2=(s+1)/ICC, ch2=(s+1)%ICC;
        const unsigned short* bp = Wb + (((size_t)((ky*KS+kx2)*ICC+ch2)*OC + l31)<<4) + hf*8;
        #pragma unroll
        for(int nn=0;nn<NTW;nn++) Bn[nn]=*(const short8*)(bp + (nn<<9));
      }
      // A frag: row m = m0 + l31 (+kx shift), k = ch*16 + hf*8 + j
      short8 a = *(const short8*)&lds[(m0 + l31 + kx)*LDR + ch*16 + hf*8];
      #pragma unroll
      for(int nn=0;nn<NTW;nn++)
        acc[nn]=__builtin_amdgcn_mfma_f32_32x32x16_bf16(a,Bc[nn],acc[nn],0,0,0);
    }
  }
  __syncthreads();

  // store: D layout col(oc)=l31, row m=(r&3)+8*(r>>2)+4*hf
  #pragma unroll
  for(int nn=0;nn<NTW;nn++){
    int oc = nn*32 + l31;
    #pragma unroll
    for(int r=0;r<16;r++){
      int m = (r&3) + 8*(r>>2) + 4*hf;
      out[(size_t)(p0+m0+m)*OC + oc] = f2b(acc[nn][r]);
    }
  }

  // BN partials (lds reuse as float scratch: 2*8*OC floats)
  float* ps=(float*)lds;
  int rps = wv*2+hf;   // 0..7
  #pragma unroll
  for(int nn=0;nn<NTW;nn++){
    float s1=0.f,s2=0.f;
    #pragma unroll
    for(int r=0;r<16;r++){ float v=acc[nn][r]; s1+=v; s2+=v*v; }
    ps[rps*OC + nn*32+l31]=s1;
    ps[(8+rps)*OC + nn*32+l31]=s2;
  }
  __syncthreads();
  if(tid<OC){
    float t1=0.f,t2=0.f;
    #pragma unroll
    for(int g=0;g<8;g++){ t1+=ps[g*OC+tid]; t2+=ps[(8+g)*OC+tid]; }
    partials[(size_t)blockIdx.x*2*OC+tid]=t1;
    partials[(size_t)blockIdx.x*2*OC+OC+tid]=t2;
  }
}

// ---------------- 16x16 MFMA implicit-GEMM conv (conv3/conv4) ----------------
template<int IC,int ICP,int OC,int KS,int TPB,int WM,int WN>
__launch_bounds__(TPB, (TPB==512)?4:3)
__global__ void mconv(const unsigned short* __restrict__ in, const unsigned short* __restrict__ Wb,
                      unsigned short* __restrict__ out, float* __restrict__ partials){
  constexpr int P=KS/2, ROWS=128+KS-1, LDR=ICP+8, ICC=ICP/32, C8=ICP/8;
  constexpr int MT = 128/(WM*16);
  constexpr int OCW = OC/WN;
  constexpr int NTW = OCW/16;
  constexpr int NS = KS*ICC;
  constexpr int RPS = WM*4;
  __shared__ __align__(16) unsigned short lds[ROWS*LDR];
  const int tid=threadIdx.x;
  const int wv=tid>>6, lane=tid&63, l15=lane&15, quad=lane>>4;
  const int wm=wv/WN, wn=wv%WN;
  const int p0=blockIdx.x*128;
  const int n=p0>>16; const int hw0=p0&65535; const int y0=hw0>>8, x0=hw0&255;

  f32x4 acc[MT][NTW];
  #pragma unroll
  for(int mt=0;mt<MT;mt++)
    #pragma unroll
    for(int nn=0;nn<NTW;nn++){ f32x4 z={0.f,0.f,0.f,0.f}; acc[mt][nn]=z; }

  for(int ky=0;ky<KS;ky++){
    int ys=y0+ky-P;
    if(ys<0||ys>255) continue;
    __syncthreads();
    for(int i=tid;i<ROWS*C8;i+=TPB){
      int c8=i%C8, px=i/C8;
      int xg=x0-P+px;
      float4 v={0.f,0.f,0.f,0.f};
      if(xg>=0 && xg<256 && c8*8<IC)
        v = *(const float4*)(in + (size_t)(((n<<16)|(ys<<8))+xg)*IC + c8*8);
      *(float4*)&lds[px*LDR + c8*8] = v;
    }
    __syncthreads();

    short8 Bn[NTW];
    {
      const unsigned short* bp = Wb + ((size_t)(((ky*KS+0)*ICC+0)*OC + wn*OCW + l15)<<5) + quad*8;
      #pragma unroll
      for(int nn=0;nn<NTW;nn++) Bn[nn]=*(const short8*)(bp + (nn<<9));
    }
    #pragma unroll
    for(int s=0;s<NS;s++){
      const int kx=s/ICC, ch=s%ICC;
      short8 Bc[NTW];
      #pragma unroll
      for(int nn=0;nn<NTW;nn++) Bc[nn]=Bn[nn];
      if(s+1<NS){
        const int kx2=(s+1)/ICC, ch2=(s+1)%ICC;
        const unsigned short* bp = Wb + ((size_t)(((ky*KS+kx2)*ICC+ch2)*OC + wn*OCW + l15)<<5) + quad*8;
        #pragma unroll
        for(int nn=0;nn<NTW;nn++) Bn[nn]=*(const short8*)(bp + (nn<<9));
      }
      short8 a[MT];
      #pragma unroll
      for(int mt=0;mt<MT;mt++)
        a[mt]=*(const short8*)&lds[(wm*(MT*16) + mt*16 + l15 + kx)*LDR + ch*32 + quad*8];
      #pragma unroll
      for(int mt=0;mt<MT;mt++)
        #pragma unroll
        for(int nn=0;nn<NTW;nn++)
          acc[mt][nn]=__builtin_amdgcn_mfma_f32_16x16x32_bf16(a[mt],Bc[nn],acc[mt][nn],0,0,0);
    }
  }
  __syncthreads();

  #pragma unroll
  for(int mt=0;mt<MT;mt++){
    int pxb = p0 + wm*(MT*16) + mt*16 + quad*4;
    #pragma unroll
    for(int nn=0;nn<NTW;nn++){
      int oc = wn*OCW + nn*16 + l15;
      #pragma unroll
      for(int r=0;r<4;r++)
        out[(size_t)(pxb+r)*OC + oc] = f2b(acc[mt][nn][r]);
    }
  }

  float* ps=(float*)lds;
  int rps = wm*4+quad;
  #pragma unroll
  for(int nn=0;nn<NTW;nn++){
    float s1=0.f,s2=0.f;
    #pragma unroll
    for(int mt=0;mt<MT;mt++)
      #pragma unroll
      for(int r=0;r<4;r++){ float v=acc[mt][nn][r]; s1+=v; s2+=v*v; }
    ps[rps*OC + wn*OCW + nn*16+l15]=s1;
    ps[(RPS+rps)*OC + wn*OCW + nn*16+l15]=s2;
  }
  __syncthreads();
  if(tid<OC){
    float t1=0.f,t2=0.f;
    #pragma unroll
    for(int g=0;g<RPS;g++){ t1+=ps[g*OC+tid]; t2+=ps[(RPS+g)*OC+tid]; }
    partials[(size_t)blockIdx.x*2*OC+tid]=t1;
    partials[(size_t)blockIdx.x*2*OC+OC+tid]=t2;
  }
}

// ---------------- BN stats finalize ----------------
__global__ void stats_kernel(const float* __restrict__ partials, const float* __restrict__ g,
                             const float* __restrict__ b, float2* __restrict__ stats, int OC, int NB){
  __shared__ float r1[256], r2[256];
  int oc=blockIdx.x; int tid=threadIdx.x;
  float s1=0.f,s2=0.f;
  for(int bl=tid;bl<NB;bl+=256){ s1+=partials[(size_t)bl*2*OC+oc]; s2+=partials[(size_t)bl*2*OC+OC+oc]; }
  r1[tid]=s1;r2[tid]=s2; __syncthreads();
  for(int s=128;s>0;s>>=1){ if(tid<s){r1[tid]+=r1[tid+s]; r2[tid]+=r2[tid+s];} __syncthreads(); }
  if(tid==0){
    float mean=r1[0]*(1.f/131072.f);
    float var =r2[0]*(1.f/131072.f)-mean*mean;
    float sc=g[oc]*rsqrtf(var+1e-5f);
    float2 st; st.x=sc; st.y=b[oc]-mean*sc;
    stats[oc]=st;
  }
}

// BN+ReLU, bf16 -> bf16 (8 channels per thread-iter)
__global__ void bnrelu_b2b(const unsigned short* __restrict__ src, unsigned short* __restrict__ dst,
                           const float2* __restrict__ stats, int OC8, int total8){
  for(int i=blockIdx.x*256+threadIdx.x;i<total8;i+=gridDim.x*256){
    int c8=i%OC8;
    float4 v=((const float4*)src)[i];
    const unsigned short* us=(const unsigned short*)&v;
    float4 o;
    unsigned short* od=(unsigned short*)&o;
    #pragma unroll
    for(int j=0;j<8;j++){
      float2 s=stats[c8*8+j];
      od[j]=f2b(fmaxf(0.f, b2f(us[j])*s.x+s.y));
    }
    ((float4*)dst)[i]=o;
  }
}

// ---------------- final 1x1 conv 48->20, bf16 in, NCHW fp32 out + bias ----------------
__global__ void obj2_kernel(const unsigned short* __restrict__ in, const float* __restrict__ w,
                            const float* __restrict__ bias, float* __restrict__ out){
  __shared__ float wsm[20*48];
  __shared__ float bs[20];
  int tid=threadIdx.x;
  for(int i=tid;i<20*48;i+=256) wsm[i]=w[i];
  if(tid<20) bs[tid]=bias[tid];
  __syncthreads();
  int p=blockIdx.x*256+tid;
  int n=p>>16, hw=p&65535;
  float x[48];
  #pragma unroll
  for(int i=0;i<6;i++){
    float4 v=*(const float4*)&in[(size_t)p*48+i*8];
    const unsigned short* us=(const unsigned short*)&v;
    #pragma unroll
    for(int j=0;j<8;j++) x[i*8+j]=b2f(us[j]);
  }
  #pragma unroll
  for(int o=0;o<20;o++){
    float s=bs[o];
    #pragma unroll
    for(int c=0;c<48;c++) s+=x[c]*wsm[o*48+c];
    out[(size_t)((n*20+o)<<16)+hw]=s;
  }
}

extern "C" void kernel_launch(void* const* d_in, const int* in_sizes, int n_in,
                              void* d_out, int out_size, void* d_ws, size_t ws_size,
                              hipStream_t stream) {
  const float* feat = (const float*)d_in[0];
  const int*   masks= (const int*)  d_in[1];
  const float* w_ih = (const float*)d_in[2];
  const float* w_hh = (const float*)d_in[3];
  const float* b_ih = (const float*)d_in[4];
  const float* b_hh = (const float*)d_in[5];
  const float* c1w  = (const float*)d_in[6];
  const float* bn1g = (const float*)d_in[7];  const float* bn1b=(const float*)d_in[8];
  const float* c2w  = (const float*)d_in[9];
  const float* bn2g = (const float*)d_in[10]; const float* bn2b=(const float*)d_in[11];
  const float* c3w  = (const float*)d_in[12];
  const float* bn3g = (const float*)d_in[13]; const float* bn3b=(const float*)d_in[14];
  const float* o1w  = (const float*)d_in[15];
  const float* bn4g = (const float*)d_in[16]; const float* bn4b=(const float*)d_in[17];
  const float* o2w  = (const float*)d_in[18]; const float* o2b =(const float*)d_in[19];

  char* ws = (char*)d_ws;
  // region0: raw conv out (bf16, max NPIX*128)
  unsigned short* Rb  = (unsigned short*)(ws + 0);          // 33554432 B
  // region1: A1b / A3b
  unsigned short* A1b = (unsigned short*)(ws + 33554432);   // 33554432 B
  unsigned short* A3b = A1b;
  // region2: Sb / A2b / A4b
  unsigned short* Sb  = (unsigned short*)(ws + 67108864);   // 33554432 B
  unsigned short* A2b = Sb;
  unsigned short* A4b = Sb;
  unsigned short* W1b = (unsigned short*)(ws + 100663296);  // 1605632 B (32-layout)
  unsigned short* W2b = (unsigned short*)(ws + 102268928);  // 147456 B (32-layout)
  unsigned short* W3b = (unsigned short*)(ws + 102416384);  // 55296 B (16-layout)
  unsigned short* W4b = (unsigned short*)(ws + 102471680);  // 55296 B (16-layout)
  unsigned short* WGb = (unsigned short*)(ws + 102526976);  // 147456 B
  float* partials = (float*)(ws + 102674432);               // 1048576 B
  float2* stats   = (float2*)(ws + 103723008);              // 1024 B
  int*   flags    = (int*)  (ws + 103724032);               // 32 B

  float* semmap = (float*)d_out;                 // [2][20][256][256]
  float* obsout = (float*)d_out + 2621440;       // [2][256][256] as float

  prep_gru_wb<<<288,256,0,stream>>>(w_ih,w_hh,WGb);
  prep_conv_w32<<<(49*8*128*16+255)/256,256,0,stream>>>(c1w,W1b,128,128,7,49*8*128*16);
  prep_conv_w32<<<(9*8*64*16 +255)/256,256,0,stream>>>(c2w,W2b,128,64,3,9*8*64*16);
  prep_conv_w<<<(9*2*48*32 +255)/256,256,0,stream>>>(c3w,W3b,64,2,48,3,9*2*48*32);
  prep_conv_w<<<(9*2*48*32 +255)/256,256,0,stream>>>(o1w,W4b,48,2,48,3,9*2*48*32);

  flags_kernel<<<8,256,0,stream>>>(masks,flags);
  obs_kernel<<<512,256,0,stream>>>(masks,flags,obsout);

  gru_mfma<<<4096,512,0,stream>>>(feat,masks,WGb,b_ih,b_hh,Sb);

  // conv1: 32x32 MFMA path, 256 threads, 4 waves x (32px x 128oc)
  m32conv<128,128,7><<<1024,256,0,stream>>>(Sb,W1b,Rb,partials);
  stats_kernel<<<128,256,0,stream>>>(partials,bn1g,bn1b,stats,128,1024);
  bnrelu_b2b<<<4096,256,0,stream>>>(Rb,A1b,stats,16,NPIX*128/8);

  // conv2: 32x32 MFMA path
  m32conv<128,64,3><<<1024,256,0,stream>>>(A1b,W2b,Rb,partials);
  stats_kernel<<<64,256,0,stream>>>(partials,bn2g,bn2b,stats,64,1024);
  bnrelu_b2b<<<4096,256,0,stream>>>(Rb,A2b,stats,8,NPIX*64/8);

  // conv3: 16x16 path
  mconv<64,64,48,3,256,4,1><<<1024,256,0,stream>>>(A2b,W3b,Rb,partials);
  stats_kernel<<<48,256,0,stream>>>(partials,bn3g,bn3b,stats,48,1024);
  bnrelu_b2b<<<4096,256,0,stream>>>(Rb,A3b,stats,6,NPIX*48/8);

  // conv4
  mconv<48,64,48,3,256,4,1><<<1024,256,0,stream>>>(A3b,W4b,Rb,partials);
  stats_kernel<<<48,256,0,stream>>>(partials,bn4g,bn4b,stats,48,1024);
  bnrelu_b2b<<<4096,256,0,stream>>>(Rb,A4b,stats,6,NPIX*48/8);

  obj2_kernel<<<512,256,0,stream>>>(A4b,o2w,o2b,semmap);
}

// Round 10
// 773.891 us; speedup vs baseline: 1.0479x; 1.0479x over previous
//
#include <hip/hip_runtime.h>
#include <hip/hip_bf16.h>
#include <math.h>

#define HWSZ 65536
#define NPIX 131072
#define LDA 208

typedef __attribute__((ext_vector_type(8))) short short8;
typedef __attribute__((ext_vector_type(4))) float f32x4;
typedef __attribute__((ext_vector_type(16))) float f32x16;

__device__ __forceinline__ float sigmf(float x){ return 1.f/(1.f+__expf(-x)); }
__device__ __forceinline__ float tanhf2(float x){
  x = fminf(fmaxf(x,-15.f),15.f);
  float e = __expf(2.f*x);
  return (e-1.f)/(e+1.f);
}
__device__ __forceinline__ unsigned short f2b(float f){
  __hip_bfloat16 b = __float2bfloat16(f);
  return *(unsigned short*)&b;
}
__device__ __forceinline__ float b2f(unsigned short u){
  unsigned int v = ((unsigned int)u)<<16;
  return __uint_as_float(v);
}

// ---------------- weight prep ----------------
__global__ void prep_gru_wb(const float* __restrict__ wih, const float* __restrict__ whh,
                            unsigned short* __restrict__ WG){
  int idx = blockIdx.x*256+threadIdx.x;
  if(idx >= 6*384*32) return;
  int kq = idx&31; int r = idx>>5;
  int c = r%384; int ch = r/384;
  int k = ch*32+kq;
  float v = (k<64) ? wih[c*64+k] : whh[c*128+(k-64)];
  WG[idx] = f2b(v);
}

// 16x16-path conv weights: [tap][chunk(ICP/32)][oc][32] bf16, zero-padded ic>=IC
__global__ void prep_conv_w(const float* __restrict__ src, unsigned short* __restrict__ dst,
                            int IC, int ICC, int OC, int KS, int total){
  int idx = blockIdx.x*256+threadIdx.x;
  if(idx>=total) return;
  int icq = idx&31; int r = idx>>5;
  int oc = r%OC; r/=OC;
  int ch = r%ICC; int tap = r/ICC;
  int ky = tap/KS, kx = tap%KS;
  int ic = ch*32+icq;
  float v = (ic<IC)? src[((oc*IC+ic)*KS+ky)*KS+kx] : 0.f;
  dst[idx] = f2b(v);
}

// 32x32-path conv weights: [tap][chunk(IC/16)][oc][16] bf16 (IC multiple of 16)
__global__ void prep_conv_w32(const float* __restrict__ src, unsigned short* __restrict__ dst,
                              int IC, int OC, int KS, int total){
  int idx = blockIdx.x*256+threadIdx.x;
  if(idx>=total) return;
  int q = idx&15; int r = idx>>4;
  int oc = r%OC; r/=OC;
  int ICC = IC/16;
  int ch = r%ICC; int tap = r/ICC;
  int ky = tap/KS, kx = tap%KS;
  int ic = ch*16+q;
  dst[idx] = f2b(src[((oc*IC+ic)*KS+ky)*KS+kx]);
}

// ---------------- mask reductions ----------------
__global__ void flags_kernel(const int* __restrict__ masks, int* __restrict__ flags){
  __shared__ int red[256];
  int b = blockIdx.x; int acc=0;
  const int* m = masks + b*HWSZ;
  for(int i=threadIdx.x;i<HWSZ;i+=256) acc |= (m[i]>0)?1:0;
  red[threadIdx.x]=acc; __syncthreads();
  for(int s=128;s>0;s>>=1){ if(threadIdx.x<s) red[threadIdx.x]|=red[threadIdx.x+s]; __syncthreads(); }
  if(threadIdx.x==0) flags[b]=red[0];
}

__global__ void obs_kernel(const int* __restrict__ masks, const int* __restrict__ flags,
                           float* __restrict__ out){
  int p = blockIdx.x*256+threadIdx.x;
  if(p>=NPIX) return;
  int n = p>>16, hw = p&65535;
  int s=0;
  #pragma unroll
  for(int t=0;t<4;t++) s += masks[((n*4+t)<<16)+hw]*flags[n*4+t];
  out[p]=(float)s;
}

// ---------------- GRU via MFMA: 512 threads, 8 waves, 32 px per block ----------------
__launch_bounds__(512,4)
__global__ void gru_mfma(const float* __restrict__ feat, const int* __restrict__ masks,
                         const unsigned short* __restrict__ WG,
                         const float* __restrict__ bih, const float* __restrict__ bhh,
                         unsigned short* __restrict__ S){
  __shared__ __align__(16) unsigned short ax[32*LDA];
  __shared__ int msk[32];
  const int tid=threadIdx.x, wv=tid>>6, lane=tid&63, l15=lane&15, quad=lane>>4;
  const int p0=blockIdx.x*32;
  const int n=p0>>16, hw0=p0&65535;
  const int j16=wv*16;

  const int j=j16+l15;
  const float brv = bih[j]     + bhh[j];
  const float bzv = bih[128+j] + bhh[128+j];
  const float binv= bih[256+j];
  const float bhnv= bhh[256+j];

  float4 z4={0.f,0.f,0.f,0.f};
  { int px=tid>>4, c8=tid&15; *(float4*)&ax[px*LDA+64+c8*8]=z4; }

  for(int t=0;t<4;t++){
    __syncthreads();
    { int px=tid>>4, c4=tid&15;
      float4 v=*(const float4*)&feat[(size_t)(((n*4+t)<<16)|(hw0+px))*64 + c4*4];
      ushort4 u; u.x=f2b(v.x);u.y=f2b(v.y);u.z=f2b(v.z);u.w=f2b(v.w);
      *(ushort4*)&ax[px*LDA+c4*4]=u;
    }
    if(tid<32) msk[tid]=masks[((n*4+t)<<16)+hw0+tid];
    __syncthreads();

    f32x4 aR[2],aZ[2],aNX[2],aNH[2];
    #pragma unroll
    for(int mt=0;mt<2;mt++){
      f32x4 zz={0.f,0.f,0.f,0.f};
      aR[mt]=zz; aZ[mt]=zz; aNX[mt]=zz; aNH[mt]=zz;
    }

    #pragma unroll
    for(int ch=0;ch<6;ch++){
      short8 a[2];
      #pragma unroll
      for(int mt=0;mt<2;mt++)
        a[mt]=*(const short8*)&ax[(mt*16+l15)*LDA + ch*32 + quad*8];
      const unsigned short* bb = WG + (((size_t)(ch*384 + l15))<<5) + quad*8;
      short8 bR=*(const short8*)(bb + (((size_t)(     j16))<<5));
      short8 bZ=*(const short8*)(bb + (((size_t)(128+j16))<<5));
      short8 bN=*(const short8*)(bb + (((size_t)(256+j16))<<5));
      #pragma unroll
      for(int mt=0;mt<2;mt++){
        aR[mt]=__builtin_amdgcn_mfma_f32_16x16x32_bf16(a[mt],bR,aR[mt],0,0,0);
        aZ[mt]=__builtin_amdgcn_mfma_f32_16x16x32_bf16(a[mt],bZ,aZ[mt],0,0,0);
        if(ch<2)
          aNX[mt]=__builtin_amdgcn_mfma_f32_16x16x32_bf16(a[mt],bN,aNX[mt],0,0,0);
        else
          aNH[mt]=__builtin_amdgcn_mfma_f32_16x16x32_bf16(a[mt],bN,aNH[mt],0,0,0);
      }
    }
    __syncthreads();

    #pragma unroll
    for(int mt=0;mt<2;mt++){
      #pragma unroll
      for(int r=0;r<4;r++){
        int px=mt*16+quad*4+r;
        float rg=sigmf(aR[mt][r]+brv);
        float zg=sigmf(aZ[mt][r]+bzv);
        float nn=tanhf2(aNX[mt][r]+binv+rg*(aNH[mt][r]+bhnv));
        unsigned short hu=ax[px*LDA+64+j];
        float hold=b2f(hu);
        float h2=(1.f-zg)*nn+zg*hold;
        ax[px*LDA+64+j] = (msk[px]>0)? f2b(h2) : hu;
      }
    }
  }
  __syncthreads();
  { int px=tid>>4, c8=tid&15;
    *(float4*)&S[(size_t)(p0+px)*128 + c8*8] = *(float4*)&ax[px*LDA+64+c8*8];
  }
}

// ---------------- 32x32 MFMA implicit-GEMM conv, 2x2 wave tiling (conv1/conv2) ----------------
// 256 threads, 4 waves tiled (wm,wn) in 2x2: wave = 64 px (2 m-tiles) x OC/2 (NTW n-tiles).
// Per K-step: 2 A ds_read_b128 + 2 B global loads feed 4 MFMAs (R=2 reuse both operands).
// Halves per-block B L2 traffic vs all-OC waves (r9's L2-bound failure).
template<int IC,int OC,int KS>
__launch_bounds__(256,3)
__global__ void m32conv(const unsigned short* __restrict__ in, const unsigned short* __restrict__ Wb,
                        unsigned short* __restrict__ out, float* __restrict__ partials){
  constexpr int P=KS/2, ROWS=128+KS-1, LDR=IC+8, ICC=IC/16, C8=IC/8;
  constexpr int OCW=OC/2, NTW=OCW/32, NS=KS*ICC;
  __shared__ __align__(16) unsigned short lds[ROWS*LDR];
  const int tid=threadIdx.x;
  const int wv=tid>>6, lane=tid&63, l31=lane&31, hf=lane>>5;
  const int wm=wv>>1, wn=wv&1;
  const int p0=blockIdx.x*128;
  const int n=p0>>16; const int hw0=p0&65535; const int y0=hw0>>8, x0=hw0&255;
  const int m0=wm*64;

  f32x16 acc[2][NTW];
  #pragma unroll
  for(int mt=0;mt<2;mt++)
    #pragma unroll
    for(int nn=0;nn<NTW;nn++){
      #pragma unroll
      for(int r=0;r<16;r++) acc[mt][nn][r]=0.f;
    }

  for(int ky=0;ky<KS;ky++){
    int ys=y0+ky-P;
    if(ys<0||ys>255) continue;          // uniform across block
    __syncthreads();
    for(int i=tid;i<ROWS*C8;i+=256){
      int c8=i%C8, px=i/C8;
      int xg=x0-P+px;
      float4 v={0.f,0.f,0.f,0.f};
      if(xg>=0 && xg<256)
        v = *(const float4*)(in + (size_t)(((n<<16)|(ys<<8))+xg)*IC + c8*8);
      *(float4*)&lds[px*LDR + c8*8] = v;
    }
    __syncthreads();

    // software-pipelined K loop over (kx, ic16-chunk)
    short8 Bn[NTW];
    {
      const unsigned short* bp = Wb + (((size_t)((ky*KS+0)*ICC+0)*OC + wn*OCW + l31)<<4) + hf*8;
      #pragma unroll
      for(int nn=0;nn<NTW;nn++) Bn[nn]=*(const short8*)(bp + (nn<<9));
    }
    #pragma unroll
    for(int s=0;s<NS;s++){
      const int kx=s/ICC, ch=s%ICC;
      short8 Bc[NTW];
      #pragma unroll
      for(int nn=0;nn<NTW;nn++) Bc[nn]=Bn[nn];
      if(s+1<NS){
        const int kx2=(s+1)/ICC, ch2=(s+1)%ICC;
        const unsigned short* bp = Wb + (((size_t)((ky*KS+kx2)*ICC+ch2)*OC + wn*OCW + l31)<<4) + hf*8;
        #pragma unroll
        for(int nn=0;nn<NTW;nn++) Bn[nn]=*(const short8*)(bp + (nn<<9));
      }
      // A frags: rows m0 + mt*32 + l31 (+kx shift), k = ch*16 + hf*8 + j
      short8 a[2];
      #pragma unroll
      for(int mt=0;mt<2;mt++)
        a[mt] = *(const short8*)&lds[(m0 + mt*32 + l31 + kx)*LDR + ch*16 + hf*8];
      #pragma unroll
      for(int mt=0;mt<2;mt++)
        #pragma unroll
        for(int nn=0;nn<NTW;nn++)
          acc[mt][nn]=__builtin_amdgcn_mfma_f32_32x32x16_bf16(a[mt],Bc[nn],acc[mt][nn],0,0,0);
    }
  }
  __syncthreads();

  // store: D layout col(oc)=l31, row m=(r&3)+8*(r>>2)+4*hf
  #pragma unroll
  for(int mt=0;mt<2;mt++){
    #pragma unroll
    for(int nn=0;nn<NTW;nn++){
      int oc = wn*OCW + nn*32 + l31;
      #pragma unroll
      for(int r=0;r<16;r++){
        int m = (r&3) + 8*(r>>2) + 4*hf;
        out[(size_t)(p0+m0+mt*32+m)*OC + oc] = f2b(acc[mt][nn][r]);
      }
    }
  }

  // BN partials (lds reuse as float scratch: 2*4*OC floats).
  // row = wm*2+hf (0..3); for each oc column exactly the 4 rows {wm,hf} write it.
  float* ps=(float*)lds;
  int rps = wm*2+hf;
  #pragma unroll
  for(int nn=0;nn<NTW;nn++){
    float s1=0.f,s2=0.f;
    #pragma unroll
    for(int mt=0;mt<2;mt++)
      #pragma unroll
      for(int r=0;r<16;r++){ float v=acc[mt][nn][r]; s1+=v; s2+=v*v; }
    ps[rps*OC + wn*OCW + nn*32+l31]=s1;
    ps[(4+rps)*OC + wn*OCW + nn*32+l31]=s2;
  }
  __syncthreads();
  if(tid<OC){
    float t1=0.f,t2=0.f;
    #pragma unroll
    for(int g=0;g<4;g++){ t1+=ps[g*OC+tid]; t2+=ps[(4+g)*OC+tid]; }
    partials[(size_t)blockIdx.x*2*OC+tid]=t1;
    partials[(size_t)blockIdx.x*2*OC+OC+tid]=t2;
  }
}

// ---------------- 16x16 MFMA implicit-GEMM conv (conv3/conv4) ----------------
template<int IC,int ICP,int OC,int KS,int TPB,int WM,int WN>
__launch_bounds__(TPB, (TPB==512)?4:3)
__global__ void mconv(const unsigned short* __restrict__ in, const unsigned short* __restrict__ Wb,
                      unsigned short* __restrict__ out, float* __restrict__ partials){
  constexpr int P=KS/2, ROWS=128+KS-1, LDR=ICP+8, ICC=ICP/32, C8=ICP/8;
  constexpr int MT = 128/(WM*16);
  constexpr int OCW = OC/WN;
  constexpr int NTW = OCW/16;
  constexpr int NS = KS*ICC;
  constexpr int RPS = WM*4;
  __shared__ __align__(16) unsigned short lds[ROWS*LDR];
  const int tid=threadIdx.x;
  const int wv=tid>>6, lane=tid&63, l15=lane&15, quad=lane>>4;
  const int wm=wv/WN, wn=wv%WN;
  const int p0=blockIdx.x*128;
  const int n=p0>>16; const int hw0=p0&65535; const int y0=hw0>>8, x0=hw0&255;

  f32x4 acc[MT][NTW];
  #pragma unroll
  for(int mt=0;mt<MT;mt++)
    #pragma unroll
    for(int nn=0;nn<NTW;nn++){ f32x4 z={0.f,0.f,0.f,0.f}; acc[mt][nn]=z; }

  for(int ky=0;ky<KS;ky++){
    int ys=y0+ky-P;
    if(ys<0||ys>255) continue;
    __syncthreads();
    for(int i=tid;i<ROWS*C8;i+=TPB){
      int c8=i%C8, px=i/C8;
      int xg=x0-P+px;
      float4 v={0.f,0.f,0.f,0.f};
      if(xg>=0 && xg<256 && c8*8<IC)
        v = *(const float4*)(in + (size_t)(((n<<16)|(ys<<8))+xg)*IC + c8*8);
      *(float4*)&lds[px*LDR + c8*8] = v;
    }
    __syncthreads();

    short8 Bn[NTW];
    {
      const unsigned short* bp = Wb + ((size_t)(((ky*KS+0)*ICC+0)*OC + wn*OCW + l15)<<5) + quad*8;
      #pragma unroll
      for(int nn=0;nn<NTW;nn++) Bn[nn]=*(const short8*)(bp + (nn<<9));
    }
    #pragma unroll
    for(int s=0;s<NS;s++){
      const int kx=s/ICC, ch=s%ICC;
      short8 Bc[NTW];
      #pragma unroll
      for(int nn=0;nn<NTW;nn++) Bc[nn]=Bn[nn];
      if(s+1<NS){
        const int kx2=(s+1)/ICC, ch2=(s+1)%ICC;
        const unsigned short* bp = Wb + ((size_t)(((ky*KS+kx2)*ICC+ch2)*OC + wn*OCW + l15)<<5) + quad*8;
        #pragma unroll
        for(int nn=0;nn<NTW;nn++) Bn[nn]=*(const short8*)(bp + (nn<<9));
      }
      short8 a[MT];
      #pragma unroll
      for(int mt=0;mt<MT;mt++)
        a[mt]=*(const short8*)&lds[(wm*(MT*16) + mt*16 + l15 + kx)*LDR + ch*32 + quad*8];
      #pragma unroll
      for(int mt=0;mt<MT;mt++)
        #pragma unroll
        for(int nn=0;nn<NTW;nn++)
          acc[mt][nn]=__builtin_amdgcn_mfma_f32_16x16x32_bf16(a[mt],Bc[nn],acc[mt][nn],0,0,0);
    }
  }
  __syncthreads();

  #pragma unroll
  for(int mt=0;mt<MT;mt++){
    int pxb = p0 + wm*(MT*16) + mt*16 + quad*4;
    #pragma unroll
    for(int nn=0;nn<NTW;nn++){
      int oc = wn*OCW + nn*16 + l15;
      #pragma unroll
      for(int r=0;r<4;r++)
        out[(size_t)(pxb+r)*OC + oc] = f2b(acc[mt][nn][r]);
    }
  }

  float* ps=(float*)lds;
  int rps = wm*4+quad;
  #pragma unroll
  for(int nn=0;nn<NTW;nn++){
    float s1=0.f,s2=0.f;
    #pragma unroll
    for(int mt=0;mt<MT;mt++)
      #pragma unroll
      for(int r=0;r<4;r++){ float v=acc[mt][nn][r]; s1+=v; s2+=v*v; }
    ps[rps*OC + wn*OCW + nn*16+l15]=s1;
    ps[(RPS+rps)*OC + wn*OCW + nn*16+l15]=s2;
  }
  __syncthreads();
  if(tid<OC){
    float t1=0.f,t2=0.f;
    #pragma unroll
    for(int g=0;g<RPS;g++){ t1+=ps[g*OC+tid]; t2+=ps[(RPS+g)*OC+tid]; }
    partials[(size_t)blockIdx.x*2*OC+tid]=t1;
    partials[(size_t)blockIdx.x*2*OC+OC+tid]=t2;
  }
}

// ---------------- BN stats finalize ----------------
__global__ void stats_kernel(const float* __restrict__ partials, const float* __restrict__ g,
                             const float* __restrict__ b, float2* __restrict__ stats, int OC, int NB){
  __shared__ float r1[256], r2[256];
  int oc=blockIdx.x; int tid=threadIdx.x;
  float s1=0.f,s2=0.f;
  for(int bl=tid;bl<NB;bl+=256){ s1+=partials[(size_t)bl*2*OC+oc]; s2+=partials[(size_t)bl*2*OC+OC+oc]; }
  r1[tid]=s1;r2[tid]=s2; __syncthreads();
  for(int s=128;s>0;s>>=1){ if(tid<s){r1[tid]+=r1[tid+s]; r2[tid]+=r2[tid+s];} __syncthreads(); }
  if(tid==0){
    float mean=r1[0]*(1.f/131072.f);
    float var =r2[0]*(1.f/131072.f)-mean*mean;
    float sc=g[oc]*rsqrtf(var+1e-5f);
    float2 st; st.x=sc; st.y=b[oc]-mean*sc;
    stats[oc]=st;
  }
}

// BN+ReLU, bf16 -> bf16 (8 channels per thread-iter)
__global__ void bnrelu_b2b(const unsigned short* __restrict__ src, unsigned short* __restrict__ dst,
                           const float2* __restrict__ stats, int OC8, int total8){
  for(int i=blockIdx.x*256+threadIdx.x;i<total8;i+=gridDim.x*256){
    int c8=i%OC8;
    float4 v=((const float4*)src)[i];
    const unsigned short* us=(const unsigned short*)&v;
    float4 o;
    unsigned short* od=(unsigned short*)&o;
    #pragma unroll
    for(int j=0;j<8;j++){
      float2 s=stats[c8*8+j];
      od[j]=f2b(fmaxf(0.f, b2f(us[j])*s.x+s.y));
    }
    ((float4*)dst)[i]=o;
  }
}

// ---------------- final 1x1 conv 48->20, bf16 in, NCHW fp32 out + bias ----------------
__global__ void obj2_kernel(const unsigned short* __restrict__ in, const float* __restrict__ w,
                            const float* __restrict__ bias, float* __restrict__ out){
  __shared__ float wsm[20*48];
  __shared__ float bs[20];
  int tid=threadIdx.x;
  for(int i=tid;i<20*48;i+=256) wsm[i]=w[i];
  if(tid<20) bs[tid]=bias[tid];
  __syncthreads();
  int p=blockIdx.x*256+tid;
  int n=p>>16, hw=p&65535;
  float x[48];
  #pragma unroll
  for(int i=0;i<6;i++){
    float4 v=*(const float4*)&in[(size_t)p*48+i*8];
    const unsigned short* us=(const unsigned short*)&v;
    #pragma unroll
    for(int j=0;j<8;j++) x[i*8+j]=b2f(us[j]);
  }
  #pragma unroll
  for(int o=0;o<20;o++){
    float s=bs[o];
    #pragma unroll
    for(int c=0;c<48;c++) s+=x[c]*wsm[o*48+c];
    out[(size_t)((n*20+o)<<16)+hw]=s;
  }
}

extern "C" void kernel_launch(void* const* d_in, const int* in_sizes, int n_in,
                              void* d_out, int out_size, void* d_ws, size_t ws_size,
                              hipStream_t stream) {
  const float* feat = (const float*)d_in[0];
  const int*   masks= (const int*)  d_in[1];
  const float* w_ih = (const float*)d_in[2];
  const float* w_hh = (const float*)d_in[3];
  const float* b_ih = (const float*)d_in[4];
  const float* b_hh = (const float*)d_in[5];
  const float* c1w  = (const float*)d_in[6];
  const float* bn1g = (const float*)d_in[7];  const float* bn1b=(const float*)d_in[8];
  const float* c2w  = (const float*)d_in[9];
  const float* bn2g = (const float*)d_in[10]; const float* bn2b=(const float*)d_in[11];
  const float* c3w  = (const float*)d_in[12];
  const float* bn3g = (const float*)d_in[13]; const float* bn3b=(const float*)d_in[14];
  const float* o1w  = (const float*)d_in[15];
  const float* bn4g = (const float*)d_in[16]; const float* bn4b=(const float*)d_in[17];
  const float* o2w  = (const float*)d_in[18]; const float* o2b =(const float*)d_in[19];

  char* ws = (char*)d_ws;
  // region0: raw conv out (bf16, max NPIX*128)
  unsigned short* Rb  = (unsigned short*)(ws + 0);          // 33554432 B
  // region1: A1b / A3b
  unsigned short* A1b = (unsigned short*)(ws + 33554432);   // 33554432 B
  unsigned short* A3b = A1b;
  // region2: Sb / A2b / A4b
  unsigned short* Sb  = (unsigned short*)(ws + 67108864);   // 33554432 B
  unsigned short* A2b = Sb;
  unsigned short* A4b = Sb;
  unsigned short* W1b = (unsigned short*)(ws + 100663296);  // 1605632 B (32-layout)
  unsigned short* W2b = (unsigned short*)(ws + 102268928);  // 147456 B (32-layout)
  unsigned short* W3b = (unsigned short*)(ws + 102416384);  // 55296 B (16-layout)
  unsigned short* W4b = (unsigned short*)(ws + 102471680);  // 55296 B (16-layout)
  unsigned short* WGb = (unsigned short*)(ws + 102526976);  // 147456 B
  float* partials = (float*)(ws + 102674432);               // 1048576 B
  float2* stats   = (float2*)(ws + 103723008);              // 1024 B
  int*   flags    = (int*)  (ws + 103724032);               // 32 B

  float* semmap = (float*)d_out;                 // [2][20][256][256]
  float* obsout = (float*)d_out + 2621440;       // [2][256][256] as float

  prep_gru_wb<<<288,256,0,stream>>>(w_ih,w_hh,WGb);
  prep_conv_w32<<<(49*8*128*16+255)/256,256,0,stream>>>(c1w,W1b,128,128,7,49*8*128*16);
  prep_conv_w32<<<(9*8*64*16 +255)/256,256,0,stream>>>(c2w,W2b,128,64,3,9*8*64*16);
  prep_conv_w<<<(9*2*48*32 +255)/256,256,0,stream>>>(c3w,W3b,64,2,48,3,9*2*48*32);
  prep_conv_w<<<(9*2*48*32 +255)/256,256,0,stream>>>(o1w,W4b,48,2,48,3,9*2*48*32);

  flags_kernel<<<8,256,0,stream>>>(masks,flags);
  obs_kernel<<<512,256,0,stream>>>(masks,flags,obsout);

  gru_mfma<<<4096,512,0,stream>>>(feat,masks,WGb,b_ih,b_hh,Sb);

  // conv1: 32x32 MFMA path, 2x2 wave tiling (64px x 64oc per wave)
  m32conv<128,128,7><<<1024,256,0,stream>>>(Sb,W1b,Rb,partials);
  stats_kernel<<<128,256,0,stream>>>(partials,bn1g,bn1b,stats,128,1024);
  bnrelu_b2b<<<4096,256,0,stream>>>(Rb,A1b,stats,16,NPIX*128/8);

  // conv2: 32x32 MFMA path, 2x2 wave tiling (64px x 32oc per wave)
  m32conv<128,64,3><<<1024,256,0,stream>>>(A1b,W2b,Rb,partials);
  stats_kernel<<<64,256,0,stream>>>(partials,bn2g,bn2b,stats,64,1024);
  bnrelu_b2b<<<4096,256,0,stream>>>(Rb,A2b,stats,8,NPIX*64/8);

  // conv3: 16x16 path
  mconv<64,64,48,3,256,4,1><<<1024,256,0,stream>>>(A2b,W3b,Rb,partials);
  stats_kernel<<<48,256,0,stream>>>(partials,bn3g,bn3b,stats,48,1024);
  bnrelu_b2b<<<4096,256,0,stream>>>(Rb,A3b,stats,6,NPIX*48/8);

  // conv4
  mconv<48,64,48,3,256,4,1><<<1024,256,0,stream>>>(A3b,W4b,Rb,partials);
  stats_kernel<<<48,256,0,stream>>>(partials,bn4g,bn4b,stats,48,1024);
  bnrelu_b2b<<<4096,256,0,stream>>>(Rb,A4b,stats,6,NPIX*48/8);

  obj2_kernel<<<512,256,0,stream>>>(A4b,o2w,o2b,semmap);
}